// Round 4
// baseline (85257.239 us; speedup 1.0000x reference)
//
#include <hip/hip_runtime.h>
#include <hip/hip_cooperative_groups.h>
#include <cstdint>

namespace cg = cooperative_groups;

#define V 32000
#define E 128
#define H 1024
#define T 64
#define B 32
#define BH (B * H)

using u64 = unsigned long long;

__device__ __forceinline__ float sigm(float x) { return 1.f / (1.f + expf(-x)); }

// ---------------- LDS layout (floats) ----------------
#define ZS_STRIDE 260
#define SMEM_FLOATS (32 * ZS_STRIDE + 256 + 64)

// Accumulate 4 gate partial dots over one staged chunk.
// wb = w + unit*WS + kc (row stride between gates = H*WS).
template <int KC, int WS>
__device__ __forceinline__ void accum_chunk(const float* __restrict__ zs,
                                            const float* __restrict__ wb,
                                            int b, int kq, float acc[4]) {
  constexpr int KQ = KC / 4;
  const float* zrow = zs + b * ZS_STRIDE + kq * KQ;
  const float* wq = wb + kq * KQ;
  #pragma unroll
  for (int ks = 0; ks < KQ; ks += 16) {
    const float4 z0 = *(const float4*)(zrow + ks);
    const float4 z1 = *(const float4*)(zrow + ks + 4);
    const float4 z2 = *(const float4*)(zrow + ks + 8);
    const float4 z3 = *(const float4*)(zrow + ks + 12);
    #pragma unroll
    for (int g = 0; g < 4; ++g) {
      const float* wp = wq + (size_t)g * (size_t)H * WS + ks;
      const float4 w0 = *(const float4*)(wp);
      const float4 w1 = *(const float4*)(wp + 4);
      const float4 w2 = *(const float4*)(wp + 8);
      const float4 w3 = *(const float4*)(wp + 12);
      acc[g] += z0.x * w0.x + z0.y * w0.y + z0.z * w0.z + z0.w * w0.w
              + z1.x * w1.x + z1.y * w1.y + z1.z * w1.z + z1.w * w1.w
              + z2.x * w2.x + z2.y * w2.y + z2.z * w2.z + z2.w * w2.w
              + z3.x * w3.x + z3.y * w3.y + z3.z * w3.z + z3.w * w3.w;
    }
  }
}

// LSTM cell (R2-validated mapping): 32 b x 4 kq x 2 units = 256 threads.
// unit = w*2 + u2.  MODE 0: x = xsrc + bb*H; 1: x = emb[tok(bb)]; 2: x = emb[src[t*B+bb]].
template <int KX, int MODE>
__device__ void cell_run(
    int w, int t, const float* __restrict__ xsrc,
    const int* __restrict__ src, const int* __restrict__ mask_i,
    const u64* __restrict__ packed,
    const float* __restrict__ wih, const float* __restrict__ whh,
    const float* __restrict__ bih, const float* __restrict__ bhh,
    const float* __restrict__ hprev, float* __restrict__ hout,
    float* __restrict__ cio, float* __restrict__ smem) {
  float* zs = smem;
  float* part = smem + 32 * ZS_STRIDE;
  int* toks = (int*)(smem + 32 * ZS_STRIDE + 256);

  const int tid = threadIdx.x;
  const int b = tid & 31;
  const int kq = (tid >> 5) & 3;
  const int u2 = tid >> 7;
  const int unit = w * 2 + u2;
  const int bb = tid >> 3, lq = tid & 7;

  if (MODE == 1) {
    if (tid < 32) {
      int tok;
      const int tm1 = t - 1;
      if (tm1 == 0) tok = src[tid];
      else if (mask_i[tm1]) tok = src[tm1 * B + tid];
      else {
        const u64* p = packed + ((size_t)tm1 * B + tid) * 8;
        u64 m = p[0];
        #pragma unroll
        for (int g = 1; g < 8; ++g) { u64 x = p[g]; m = m > x ? m : x; }
        tok = (int)(0xFFFFFFFFu - (unsigned)(m & 0xFFFFFFFFull));
      }
      toks[tid] = tok;
    }
    __syncthreads();
  }

  float acc[4] = {0.f, 0.f, 0.f, 0.f};

  // ---- phase X ----
  {
    const float* rowb = (MODE == 0) ? xsrc + (size_t)bb * H
                      : (MODE == 1) ? xsrc + (size_t)toks[bb] * E
                                    : xsrc + (size_t)src[t * B + bb] * E;
    constexpr int KC = (KX >= 256) ? 256 : KX;
    #pragma unroll 1
    for (int kc = 0; kc < KX; kc += KC) {
      #pragma unroll
      for (int j = lq; j < KC / 4; j += 8)
        *(float4*)(zs + bb * ZS_STRIDE + 4 * j) = *(const float4*)(rowb + kc + 4 * j);
      __syncthreads();
      accum_chunk<KC, KX>(zs, wih + (size_t)unit * KX + kc, b, kq, acc);
      __syncthreads();
    }
  }
  // ---- phase H ----
  {
    const float* rowb = hprev + (size_t)bb * H;
    #pragma unroll 1
    for (int kc = 0; kc < H; kc += 256) {
      #pragma unroll
      for (int j = lq; j < 64; j += 8)
        *(float4*)(zs + bb * ZS_STRIDE + 4 * j) = *(const float4*)(rowb + kc + 4 * j);
      __syncthreads();
      accum_chunk<256, H>(zs, whh + (size_t)unit * H + kc, b, kq, acc);
      __syncthreads();
    }
  }

  #pragma unroll
  for (int g = 0; g < 4; ++g) acc[g] += __shfl_xor(acc[g], 32);
  if (kq == 2)
    *(float4*)(part + (u2 * 32 + b) * 4) = make_float4(acc[0], acc[1], acc[2], acc[3]);
  __syncthreads();
  if (kq == 0) {
    const float4 p = *(const float4*)(part + (u2 * 32 + b) * 4);
    float gi = acc[0] + p.x + bih[unit]         + bhh[unit];
    float gf = acc[1] + p.y + bih[H + unit]     + bhh[H + unit];
    float gg = acc[2] + p.z + bih[2 * H + unit] + bhh[2 * H + unit];
    float go = acc[3] + p.w + bih[3 * H + unit] + bhh[3 * H + unit];
    float c = cio[b * H + unit];
    c = sigm(gf) * c + sigm(gi) * tanhf(gg);
    cio[b * H + unit] = c;
    hout[b * H + unit] = sigm(go) * tanhf(c);
  }
}

// ---------------- FC work unit w: v-range [w*64, w*64+64) ----------------

#define VPT 8
#define VB 64

__device__ void fc_run(int w, int t, const float* __restrict__ fc_w,
                       const float* __restrict__ fc_b, const float* __restrict__ h,
                       float* __restrict__ out, u64* __restrict__ packed,
                       float* __restrict__ smem) {
  float* hs = smem;                       // 32*132; later reused as out tile [32][68]
  u64* red = (u64*)(smem + 32 * 132);     // 8*32 u64
  const int tid = threadIdx.x;
  const int b = tid & 31;
  const int vl = tid >> 5;
  const int v0 = w * VB;

  float4 acc[VPT];
  #pragma unroll
  for (int q = 0; q < VPT; ++q) acc[q] = make_float4(0.f, 0.f, 0.f, 0.f);

  #pragma unroll 1
  for (int kc = 0; kc < H; kc += 128) {
    __syncthreads();
    {
      const int bb = tid >> 3;
      const int kk = (tid & 7) << 4;
      const float* gp = h + (size_t)bb * H + kc + kk;
      float4 x0 = *(const float4*)(gp);
      float4 x1 = *(const float4*)(gp + 4);
      float4 x2 = *(const float4*)(gp + 8);
      float4 x3 = *(const float4*)(gp + 12);
      float* s = hs + bb * 132 + kk;
      *(float4*)(s) = x0; *(float4*)(s + 4) = x1;
      *(float4*)(s + 8) = x2; *(float4*)(s + 12) = x3;
    }
    __syncthreads();
    const float* hb = hs + b * 132;
    #pragma unroll
    for (int ks = 0; ks < 128; ks += 16) {
      const float4 x0 = *(const float4*)(hb + ks);
      const float4 x1 = *(const float4*)(hb + ks + 4);
      const float4 x2 = *(const float4*)(hb + ks + 8);
      const float4 x3 = *(const float4*)(hb + ks + 12);
      #pragma unroll
      for (int q = 0; q < VPT; ++q) {
        const float* wp = fc_w + (size_t)(v0 + (q << 3) + vl) * H + kc + ks;
        const float4 w0 = *(const float4*)(wp);
        const float4 w1 = *(const float4*)(wp + 4);
        const float4 w2 = *(const float4*)(wp + 8);
        const float4 w3 = *(const float4*)(wp + 12);
        acc[q].x += x0.x * w0.x; acc[q].y += x0.y * w0.y; acc[q].z += x0.z * w0.z; acc[q].w += x0.w * w0.w;
        acc[q].x += x1.x * w1.x; acc[q].y += x1.y * w1.y; acc[q].z += x1.z * w1.z; acc[q].w += x1.w * w1.w;
        acc[q].x += x2.x * w2.x; acc[q].y += x2.y * w2.y; acc[q].z += x2.z * w2.z; acc[q].w += x2.w * w2.w;
        acc[q].x += x3.x * w3.x; acc[q].y += x3.y * w3.y; acc[q].z += x3.z * w3.z; acc[q].w += x3.w * w3.w;
      }
    }
  }

  u64 best = 0ull;
  float vals[VPT];
  #pragma unroll
  for (int q = 0; q < VPT; ++q) {
    const int v = v0 + (q << 3) + vl;
    float val = ((acc[q].x + acc[q].y) + (acc[q].z + acc[q].w)) + fc_b[v];
    vals[q] = val;
    unsigned uu = __float_as_uint(val);
    uu = (uu & 0x80000000u) ? ~uu : (uu | 0x80000000u);
    u64 pk = ((u64)uu << 32) | (u64)(0xFFFFFFFFu - (unsigned)v);  // ties -> smallest v
    best = best > pk ? best : pk;
  }
  red[vl * 32 + b] = best;
  __syncthreads();

  float* tile = hs;                        // [32][68]
  #pragma unroll
  for (int q = 0; q < VPT; ++q) tile[b * 68 + (q << 3) + vl] = vals[q];

  if (tid < 32) {
    u64 m = red[tid];
    #pragma unroll
    for (int q = 1; q < 8; ++q) { u64 x = red[q * 32 + tid]; m = m > x ? m : x; }
    atomicMax(&packed[((size_t)t * B + tid) * 8 + (w & 7)], m);
  }
  __syncthreads();
  {
    const int bb = tid >> 3, j = tid & 7;
    const float4 o0 = *(const float4*)(tile + bb * 68 + j * 8);
    const float4 o1 = *(const float4*)(tile + bb * 68 + j * 8 + 4);
    float* op = out + (size_t)t * (B * V) + (size_t)bb * V + v0 + j * 8;
    *(float4*)op = o0;
    *(float4*)(op + 4) = o1;
  }
}

// ---------------- phase work units ----------------

// encoder tick: w in [0,1024): w<512 -> L0 unit-pair w @ step t; else L1 pair @ step t-1
__device__ __forceinline__ void enc_work(
    int w, int t, const int* __restrict__ src, const float* __restrict__ emb_enc,
    const float* __restrict__ e_wih0, const float* __restrict__ e_whh0,
    const float* __restrict__ e_bih0, const float* __restrict__ e_bhh0,
    const float* __restrict__ e_wih1, const float* __restrict__ e_whh1,
    const float* __restrict__ e_bih1, const float* __restrict__ e_bhh1,
    float* __restrict__ ys0, float* __restrict__ h1e,
    float* __restrict__ c0, float* __restrict__ c1, float* __restrict__ smem) {
  if (w < 512) {
    if (t < T)
      cell_run<E, 2>(w, t, emb_enc, src, nullptr, nullptr,
                     e_wih0, e_whh0, e_bih0, e_bhh0,
                     ys0 + (size_t)((t + 1) & 1) * BH,
                     ys0 + (size_t)(t & 1) * BH, c0, smem);
  } else {
    const int s = t - 1;
    if (s >= 0)
      cell_run<H, 0>(w - 512, s, ys0 + (size_t)(s & 1) * BH, src, nullptr, nullptr,
                     e_wih1, e_whh1, e_bih1, e_bhh1,
                     h1e + (size_t)((s + 1) & 1) * BH,
                     h1e + (size_t)(s & 1) * BH, c1, smem);
  }
}

__device__ __forceinline__ void init_work(
    int g, float* __restrict__ ys0, float* __restrict__ h1e,
    float* __restrict__ c0, float* __restrict__ c1,
    u64* __restrict__ packed, float* __restrict__ out) {
  if (g < BH) { ys0[BH + g] = 0.f; h1e[BH + g] = 0.f; c0[g] = 0.f; c1[g] = 0.f; }
  if (g < T * B * 8) packed[g] = 0ull;
  if (g < (B * V) / 8) {
    float* p = out + (size_t)g * 8;
    *(float4*)p = make_float4(0.f, 0.f, 0.f, 0.f);
    *(float4*)(p + 4) = make_float4(0.f, 0.f, 0.f, 0.f);
  }
}

__device__ __forceinline__ void mask_work(const unsigned char* __restrict__ tfm,
                                          int* __restrict__ mask_i, int* __restrict__ sh) {
  const int tid = threadIdx.x;
  if (tid == 0) {
    int cnt = 0;
    for (int i = 0; i < 64; ++i)
      if ((i & 3) && tfm[i]) cnt++;     // i32 layout never nonzero at i%4!=0
    sh[0] = (cnt > 0) ? 1 : 0;
  }
  __syncthreads();
  if (tid < T)
    mask_i[tid] = sh[0] ? (tfm[tid] ? 1 : 0) : (((const int*)tfm)[tid] ? 1 : 0);
}

// ---------------- persistent cooperative mega-kernel (any grid size) ----------------

__global__ __launch_bounds__(256, 2) void mega(
    const int* __restrict__ src, const unsigned char* __restrict__ tfm,
    const float* __restrict__ emb_enc, const float* __restrict__ emb_dec,
    const float* __restrict__ fc_w, const float* __restrict__ fc_b,
    const float* __restrict__ e_wih0, const float* __restrict__ e_whh0,
    const float* __restrict__ e_bih0, const float* __restrict__ e_bhh0,
    const float* __restrict__ e_wih1, const float* __restrict__ e_whh1,
    const float* __restrict__ e_bih1, const float* __restrict__ e_bhh1,
    const float* __restrict__ d_wih0, const float* __restrict__ d_whh0,
    const float* __restrict__ d_bih0, const float* __restrict__ d_bhh0,
    const float* __restrict__ d_wih1, const float* __restrict__ d_whh1,
    const float* __restrict__ d_bih1, const float* __restrict__ d_bhh1,
    float* __restrict__ out,
    float* __restrict__ ys0, float* __restrict__ h1e,
    float* __restrict__ h0d, float* __restrict__ h1d,
    float* __restrict__ c0, float* __restrict__ c1,
    u64* __restrict__ packed, int* __restrict__ mask_i) {
  cg::grid_group grid = cg::this_grid();
  __shared__ float smem[SMEM_FLOATS];
  const int tid = threadIdx.x;
  const int bid = blockIdx.x;
  const int gsz = gridDim.x;

  for (int g = bid * 256 + tid; g < (B * V) / 8; g += gsz * 256)
    init_work(g, ys0, h1e, c0, c1, packed, out);
  if (bid == 0) mask_work(tfm, mask_i, (int*)smem);
  grid.sync();

  for (int t = 0; t <= T; ++t) {
    for (int w = bid; w < 1024; w += gsz)
      enc_work(w, t, src, emb_enc, e_wih0, e_whh0, e_bih0, e_bhh0,
               e_wih1, e_whh1, e_bih1, e_bhh1, ys0, h1e, c0, c1, smem);
    grid.sync();
  }

  for (int t = 1; t < T; ++t) {
    {
      const float* hp = (t == 1) ? (ys0 + (size_t)BH)
                                 : (h0d + (size_t)((t - 1) & 1) * BH);
      for (int w = bid; w < 512; w += gsz)
        cell_run<E, 1>(w, t, emb_dec, src, mask_i, packed,
                       d_wih0, d_whh0, d_bih0, d_bhh0,
                       hp, h0d + (size_t)(t & 1) * BH, c0, smem);
    }
    grid.sync();
    {
      const float* hp = (t == 1) ? (h1e + (size_t)BH)
                                 : (h1d + (size_t)((t - 1) & 1) * BH);
      for (int w = bid; w < 512; w += gsz)
        cell_run<H, 0>(w, t, h0d + (size_t)(t & 1) * BH, src, nullptr, nullptr,
                       d_wih1, d_whh1, d_bih1, d_bhh1,
                       hp, h1d + (size_t)(t & 1) * BH, c1, smem);
    }
    grid.sync();
    for (int w = bid; w < 500; w += gsz)
      fc_run(w, t, fc_w, fc_b, h1d + (size_t)(t & 1) * BH, out, packed, smem);
    grid.sync();
  }
}

// ---------------- fallback wrappers (multi-kernel path, R2-equivalent) ----------------

__global__ __launch_bounds__(256) void k_init(
    float* __restrict__ ys0, float* __restrict__ h1e,
    float* __restrict__ c0, float* __restrict__ c1,
    u64* __restrict__ packed, float* __restrict__ out,
    const unsigned char* __restrict__ tfm, int* __restrict__ mask_i) {
  __shared__ int sh[1];
  const int g = blockIdx.x * 256 + threadIdx.x;     // grid 512 covers 131072 >= 128000
  if (g < (B * V) / 8) init_work(g, ys0, h1e, c0, c1, packed, out);
  if (blockIdx.x == 0) mask_work(tfm, mask_i, sh);
}

__global__ __launch_bounds__(256, 2) void k_enc(
    int t, const int* __restrict__ src, const float* __restrict__ emb_enc,
    const float* __restrict__ e_wih0, const float* __restrict__ e_whh0,
    const float* __restrict__ e_bih0, const float* __restrict__ e_bhh0,
    const float* __restrict__ e_wih1, const float* __restrict__ e_whh1,
    const float* __restrict__ e_bih1, const float* __restrict__ e_bhh1,
    float* __restrict__ ys0, float* __restrict__ h1e,
    float* __restrict__ c0, float* __restrict__ c1) {
  __shared__ float smem[SMEM_FLOATS];
  enc_work(blockIdx.x, t, src, emb_enc, e_wih0, e_whh0, e_bih0, e_bhh0,
           e_wih1, e_whh1, e_bih1, e_bhh1, ys0, h1e, c0, c1, smem);
}

__global__ __launch_bounds__(256, 2) void k_deca(
    int t, const int* __restrict__ src, const int* __restrict__ mask_i,
    const u64* __restrict__ packed, const float* __restrict__ emb_dec,
    const float* __restrict__ d_wih0, const float* __restrict__ d_whh0,
    const float* __restrict__ d_bih0, const float* __restrict__ d_bhh0,
    const float* __restrict__ ys0, float* __restrict__ h0d, float* __restrict__ c0) {
  __shared__ float smem[SMEM_FLOATS];
  const float* hp = (t == 1) ? (ys0 + (size_t)BH)
                             : (h0d + (size_t)((t - 1) & 1) * BH);
  cell_run<E, 1>(blockIdx.x, t, emb_dec, src, mask_i, packed,
                 d_wih0, d_whh0, d_bih0, d_bhh0,
                 hp, h0d + (size_t)(t & 1) * BH, c0, smem);
}

__global__ __launch_bounds__(256, 2) void k_decb(
    int t, const float* __restrict__ d_wih1, const float* __restrict__ d_whh1,
    const float* __restrict__ d_bih1, const float* __restrict__ d_bhh1,
    const float* __restrict__ h0d, const float* __restrict__ h1e,
    float* __restrict__ h1d, float* __restrict__ c1) {
  __shared__ float smem[SMEM_FLOATS];
  const float* hp = (t == 1) ? (h1e + (size_t)BH)
                             : (h1d + (size_t)((t - 1) & 1) * BH);
  cell_run<H, 0>(blockIdx.x, t, h0d + (size_t)(t & 1) * BH, nullptr, nullptr, nullptr,
                 d_wih1, d_whh1, d_bih1, d_bhh1,
                 hp, h1d + (size_t)(t & 1) * BH, c1, smem);
}

__global__ __launch_bounds__(256, 2) void k_fc(
    int t, const float* __restrict__ fc_w, const float* __restrict__ fc_b,
    const float* __restrict__ h1d, float* __restrict__ out, u64* __restrict__ packed) {
  __shared__ float smem[SMEM_FLOATS];
  fc_run(blockIdx.x, t, fc_w, fc_b, h1d + (size_t)(t & 1) * BH, out, packed, smem);
}

// ---------------- host ----------------

extern "C" void kernel_launch(void* const* d_in, const int* in_sizes, int n_in,
                              void* d_out, int out_size, void* d_ws, size_t ws_size,
                              hipStream_t stream) {
  const int*           src     = (const int*)d_in[0];
  const unsigned char* tfm     = (const unsigned char*)d_in[1];
  const float* emb_enc = (const float*)d_in[2];
  const float* emb_dec = (const float*)d_in[3];
  const float* fc_w    = (const float*)d_in[4];
  const float* fc_b    = (const float*)d_in[5];
  const float* e_wih0  = (const float*)d_in[6];
  const float* e_whh0  = (const float*)d_in[7];
  const float* e_bih0  = (const float*)d_in[8];
  const float* e_bhh0  = (const float*)d_in[9];
  const float* e_wih1  = (const float*)d_in[10];
  const float* e_whh1  = (const float*)d_in[11];
  const float* e_bih1  = (const float*)d_in[12];
  const float* e_bhh1  = (const float*)d_in[13];
  const float* d_wih0  = (const float*)d_in[14];
  const float* d_whh0  = (const float*)d_in[15];
  const float* d_bih0  = (const float*)d_in[16];
  const float* d_bhh0  = (const float*)d_in[17];
  const float* d_wih1  = (const float*)d_in[18];
  const float* d_whh1  = (const float*)d_in[19];
  const float* d_bih1  = (const float*)d_in[20];
  const float* d_bhh1  = (const float*)d_in[21];

  float* out = (float*)d_out;
  float* wsf = (float*)d_ws;

  float* ys0 = wsf;                         // [2][B][H]
  float* h1e = ys0 + 2 * BH;                // [2][B][H]
  float* h0d = h1e + 2 * BH;                // [2][B][H]
  float* h1d = h0d + 2 * BH;                // [2][B][H]
  float* c0  = h1d + 2 * BH;                // [B][H]
  float* c1  = c0 + BH;                     // [B][H]
  u64*   packed = (u64*)(c1 + BH);          // [T][B][8]
  int*   mask_i = (int*)(packed + (size_t)T * B * 8);

  // ---- try cooperative mega-kernel with a measured grid size ----
  int dev = 0;
  (void)hipGetDevice(&dev);
  int ncu = 0;
  (void)hipDeviceGetAttribute(&ncu, hipDeviceAttributeMultiprocessorCount, dev);
  int occ = 0;
  hipError_t oe = hipOccupancyMaxActiveBlocksPerMultiprocessor(&occ, (const void*)mega, 256, 0);

  hipError_t le = hipErrorUnknown;
  if (oe == hipSuccess && occ > 0 && ncu > 0) {
    int gridN = occ * ncu;
    if (gridN > 512) gridN = 512;
    void* args[] = {
      (void*)&src, (void*)&tfm, (void*)&emb_enc, (void*)&emb_dec,
      (void*)&fc_w, (void*)&fc_b,
      (void*)&e_wih0, (void*)&e_whh0, (void*)&e_bih0, (void*)&e_bhh0,
      (void*)&e_wih1, (void*)&e_whh1, (void*)&e_bih1, (void*)&e_bhh1,
      (void*)&d_wih0, (void*)&d_whh0, (void*)&d_bih0, (void*)&d_bhh0,
      (void*)&d_wih1, (void*)&d_whh1, (void*)&d_bih1, (void*)&d_bhh1,
      (void*)&out, (void*)&ys0, (void*)&h1e, (void*)&h0d, (void*)&h1d,
      (void*)&c0, (void*)&c1, (void*)&packed, (void*)&mask_i
    };
    le = hipLaunchCooperativeKernel((void*)mega, dim3(gridN), dim3(256), args, 0, stream);
    if (le != hipSuccess && gridN > 256)
      le = hipLaunchCooperativeKernel((void*)mega, dim3(256), dim3(256), args, 0, stream);
  }

  if (le != hipSuccess) {
    // ---- fallback: R2-style multi-kernel path ----
    k_init<<<512, 256, 0, stream>>>(ys0, h1e, c0, c1, packed, out, tfm, mask_i);
    for (int t = 0; t <= T; ++t)
      k_enc<<<1024, 256, 0, stream>>>(t, src, emb_enc,
                                      e_wih0, e_whh0, e_bih0, e_bhh0,
                                      e_wih1, e_whh1, e_bih1, e_bhh1,
                                      ys0, h1e, c0, c1);
    for (int t = 1; t < T; ++t) {
      k_deca<<<512, 256, 0, stream>>>(t, src, mask_i, packed, emb_dec,
                                      d_wih0, d_whh0, d_bih0, d_bhh0,
                                      ys0, h0d, c0);
      k_decb<<<512, 256, 0, stream>>>(t, d_wih1, d_whh1, d_bih1, d_bhh1,
                                      h0d, h1e, h1d, c1);
      k_fc<<<500, 256, 0, stream>>>(t, fc_w, fc_b, h1d, out, packed);
    }
  }
}